// Round 11
// baseline (123.353 us; speedup 1.0000x reference)
//
#include <hip/hip_runtime.h>
#include <cmath>

// GRU-D cell: B=16384, F=U=512.
//   prep_pack: xd,hd -> A1=[xd|hd] bf16 (B x 1024); weights -> bf16 B^T
//   gemm5<0>: A1 @ Wzr -> sigmoid -> Zb (bf16), RH = r*hd (bf16)  [256x256]
//   gemm5<1>: [xd|RH] @ Wht -> tanh, blend with Zb, hd from A1 -> out [256x128]
// R11: single change vs R10 -- prep's 16 row-loads pinned live via empty
// asm "+v" ties after issue. R10 evidence: VGPR stayed 32 (compiler sank
// loads to uses, ~1 load in flight/wave -> 1.76 TB/s, Little's-law match).
// asm consume forces all loads concurrently outstanding.
// gemm5 kernels unchanged (passed 3x; at m97-family staging ceiling).

typedef __bf16 bf16x8 __attribute__((ext_vector_type(8)));
typedef __bf16 bf16x4 __attribute__((ext_vector_type(4)));
typedef float f32x4 __attribute__((ext_vector_type(4)));

typedef __attribute__((address_space(3))) void lds_vp;
typedef const __attribute__((address_space(1))) void g_vp;

#define VMC(N) asm volatile("s_waitcnt vmcnt(" N ")" ::: "memory")

__device__ __forceinline__ void barrier_() {
  asm volatile("" ::: "memory");
  __builtin_amdgcn_s_barrier();
  asm volatile("" ::: "memory");
}

#define KEEP4(v)                                                        \
  asm volatile("" : "+v"((v).x), "+v"((v).y), "+v"((v).z), "+v"((v).w))

__device__ __forceinline__ float sigmoidf_(float x) { return 1.f / (1.f + expf(-x)); }

// ---------------- prep (forced-MLP) + pack (LDS transpose) ----------------
__global__ __launch_bounds__(256, 4) void prep_pack_k(
    const float* __restrict__ inp, const float* __restrict__ h_prev,
    const float* __restrict__ gxd, const float* __restrict__ ghd,
    const float* __restrict__ mimp, __bf16* __restrict__ A1,
    const float* __restrict__ Wz, const float* __restrict__ Uz,
    const float* __restrict__ Wr, const float* __restrict__ Ur,
    const float* __restrict__ Wh, const float* __restrict__ Uh,
    __bf16* __restrict__ Wzr, __bf16* __restrict__ Wht) {
  __shared__ __bf16 T[64][65];
  int tid = threadIdx.x;
  if (blockIdx.x < 2048) {
    int base = blockIdx.x * 256 + tid;         // 524288 threads
    int c4 = (base & 127) << 2;                // fixed column quad
    int r0 = base >> 7;                        // rows r0 + 4096*u
    float4 gxv = *(const float4*)(gxd + c4);
    float4 ghv = *(const float4*)(ghd + c4);
    float4 miv = *(const float4*)(mimp + c4);
    // 16 independent row loads, all forced live simultaneously
    float4 xv[4], mv[4], dv[4], hv[4];
#pragma unroll
    for (int u = 0; u < 4; ++u) {
      int row = r0 + u * 4096;
      const float* ir = inp + (size_t)row * 1536 + c4;
      xv[u] = *(const float4*)(ir);
      mv[u] = *(const float4*)(ir + 512);
      dv[u] = *(const float4*)(ir + 1024);
      hv[u] = *(const float4*)(h_prev + (size_t)row * 512 + c4);
    }
    KEEP4(gxv); KEEP4(ghv); KEEP4(miv);
#pragma unroll
    for (int u = 0; u < 4; ++u) {
      KEEP4(xv[u]); KEEP4(mv[u]); KEEP4(dv[u]); KEEP4(hv[u]);
    }
    float gxc[4], ghc[4], mi[4];
#pragma unroll
    for (int j = 0; j < 4; ++j) {
      gxc[j] = -fmaxf(0.f, ((const float*)&gxv)[j]);
      ghc[j] = -fmaxf(0.f, ((const float*)&ghv)[j]);
      mi[j] = ((const float*)&miv)[j];
    }
#pragma unroll
    for (int u = 0; u < 4; ++u) {
      int row = r0 + u * 4096;
      bf16x4 xo, ho;
#pragma unroll
      for (int j = 0; j < 4; ++j) {
        float x = ((const float*)&xv[u])[j];
        float m = ((const float*)&mv[u])[j];
        float d = ((const float*)&dv[u])[j];
        float h = ((const float*)&hv[u])[j];
        float g  = __expf(gxc[j] * d);
        float xd = m * x + (1.f - m) * (g * x + (1.f - g) * mi[j]);
        float hd = __expf(ghc[j] * d) * h;
        xo[j] = (__bf16)xd;
        ho[j] = (__bf16)hd;
      }
      *(bf16x4*)(A1 + (size_t)row * 1024 + c4) = xo;
      *(bf16x4*)(A1 + (size_t)row * 1024 + 512 + c4) = ho;
    }
  } else {
    // pack one 64x64 (k,n) tile, transposed, into dst[n][k] (ldk=1024)
    int bid = blockIdx.x - 2048;
    const float* S;
    __bf16* dst;
    int tk, tn, nadj;
    if (bid < 256) {           // Wzr: 16 k-tiles x 16 n-tiles
      tk = (bid >> 4) * 64; tn = (bid & 15) * 64;
      bool khi = tk >= 512, nhi = tn >= 512;
      S = nhi ? (khi ? Ur : Wr) : (khi ? Uz : Wz);
      nadj = nhi ? 512 : 0;
      dst = Wzr;
    } else {                   // Wht: 16 k-tiles x 8 n-tiles
      int b2 = bid - 256;
      tk = (b2 >> 3) * 64; tn = (b2 & 7) * 64;
      S = (tk >= 512) ? Uh : Wh;
      nadj = 0;
      dst = Wht;
    }
    int kadj = (tk >= 512) ? 512 : 0;
    int kl = tid >> 4, n4 = (tid & 15) << 2;
#pragma unroll
    for (int rr = 0; rr < 4; ++rr) {
      int k = rr * 16 + kl;
      float4 v = *(const float4*)(S + (size_t)(tk - kadj + k) * 512 + (tn - nadj) + n4);
      T[k][n4 + 0] = (__bf16)v.x;
      T[k][n4 + 1] = (__bf16)v.y;
      T[k][n4 + 2] = (__bf16)v.z;
      T[k][n4 + 3] = (__bf16)v.w;
    }
    __syncthreads();
    int k0 = (tid & 7) * 8;
#pragma unroll
    for (int h = 0; h < 2; ++h) {
      int nl = (tid >> 3) + h * 32;
      bf16x8 v;
#pragma unroll
      for (int i = 0; i < 8; ++i) v[i] = T[k0 + i][nl];
      *(bf16x8*)(dst + (size_t)(tn + nl) * 1024 + tk + k0) = v;
    }
  }
}

// ---------------- 3-buffer GEMM (BM=256, BK=32, one block-round) ----------------
// LDS packed layout (16B units): logical element (row m, 16B k-chunk ku in 0..3)
// stored at unit (m>>1)*8 + (((m&1)*4 + ku) ^ ((m>>1)&7)).
// Staging writes linear units; per-lane global source applies the inverse map.

template <int MODE>
__global__ __launch_bounds__(512, 1) void gemm5_k(
    const __bf16* __restrict__ A1, const __bf16* __restrict__ RH,
    const __bf16* __restrict__ Bt,
    __bf16* __restrict__ Zb, __bf16* __restrict__ RHout,
    const float* __restrict__ bza, const float* __restrict__ bzb,
    float* __restrict__ out) {
  constexpr int NI = (MODE == 0) ? 8 : 4;     // n-frags per wave
  constexpr int BN = NI * 32;                 // 256 / 128
  constexpr int BUNITS = BN * 4;              // B 16B-units per tile
  constexpr int SBUF = 1024 + BUNITS;         // A 1024 | B
  __shared__ bf16x8 ldsv[3 * SBUF];           // 96KB / 72KB
  constexpr int NT = 32;                      // K=1024, BK=32
#define VMC_STEADY() do { if constexpr (MODE == 0) { VMC("4"); } else { VMC("3"); } } while (0)

  int bid = blockIdx.x;
  int swz = (bid & 7) * 32 + (bid >> 3);      // bijective XCD swizzle (256=8x32)
  int bm = swz >> 2, bn = swz & 3;            // 64 x 4
  int tid = threadIdx.x, lane = tid & 63, wid = tid >> 6;
  int wm = wid >> 1, wn = wid & 1;            // 4M x 2N waves: 64 x (NI*16)

  // per-lane staging source offsets (inverse of packed-swizzle map)
  auto inv = [&](int U, int ldb) {
    int r = U >> 3, s = (U & 7) ^ (r & 7);
    return (2 * r + (s >> 2)) * ldb + (s & 3) * 16;  // bytes
  };
  int UA0 = wid * 128 + lane, UA1 = UA0 + 64;
  int offA0 = inv(UA0, 2048), offA1 = inv(UA1, 2048);
  int offA0r = inv(UA0, 1024), offA1r = inv(UA1, 1024);  // MODE1 RH half
  int UB0 = (MODE == 0) ? (wid * 128 + lane) : (wid * 64 + lane);
  int offB0 = inv(UB0, 2048);
  int offB1 = (MODE == 0) ? inv(UB0 + 64, 2048) : 0;
  int ldsB = (MODE == 0) ? (wid * 128) : (wid * 64);   // wave-uniform

  auto stage = [&](int t, int buf) {
    const char* gA;
    int oA0, oA1;
    if (MODE == 0 || t < 16) {
      gA = (const char*)A1 + (size_t)bm * 256 * 2048 + t * 64;
      oA0 = offA0; oA1 = offA1;
    } else {
      gA = (const char*)RH + (size_t)bm * 256 * 1024 + (t - 16) * 64;
      oA0 = offA0r; oA1 = offA1r;
    }
    __builtin_amdgcn_global_load_lds((g_vp*)(gA + oA0),
        (lds_vp*)(ldsv + buf * SBUF + wid * 128), 16, 0, 0);
    __builtin_amdgcn_global_load_lds((g_vp*)(gA + oA1),
        (lds_vp*)(ldsv + buf * SBUF + wid * 128 + 64), 16, 0, 0);
    const char* gB = (const char*)Bt + (size_t)bn * BN * 2048 + t * 64;
    __builtin_amdgcn_global_load_lds((g_vp*)(gB + offB0),
        (lds_vp*)(ldsv + buf * SBUF + 1024 + ldsB), 16, 0, 0);
    if constexpr (MODE == 0) {
      __builtin_amdgcn_global_load_lds((g_vp*)(gB + offB1),
          (lds_vp*)(ldsv + buf * SBUF + 1024 + ldsB + 64), 16, 0, 0);
    }
  };

  // fragment read bases (16B units), loop-invariant
  int lr = (lane & 15) >> 1;
  int lo = ((lane & 1) << 2) | (lane >> 4);
  int aoff = lr * 8 + (lo ^ lr);
  int aB = wm * 256 + aoff;                   // + mf*64
  int bB = 1024 + wn * (NI * 64) + aoff;      // + nf*64

  f32x4 acc[4][NI] = {};

  stage(0, 0);
  stage(1, 1);
  VMC_STEADY();
  barrier_();

  int rb = 0, sb = 2;
  for (int t = 0; t < NT; ++t) {
    int base = rb * SBUF;
    if (t + 2 < NT) stage(t + 2, sb);

    bf16x8 bf[NI];
#pragma unroll
    for (int nf = 0; nf < NI; ++nf) bf[nf] = ldsv[base + bB + nf * 64];
    __builtin_amdgcn_s_setprio(1);
#pragma unroll
    for (int mf = 0; mf < 4; ++mf) {
      bf16x8 a = ldsv[base + aB + mf * 64];
#pragma unroll
      for (int nf = 0; nf < NI; ++nf)
        acc[mf][nf] = __builtin_amdgcn_mfma_f32_16x16x32_bf16(a, bf[nf],
                                                              acc[mf][nf], 0, 0, 0);
    }
    __builtin_amdgcn_s_setprio(0);

    if (t + 2 < NT) { VMC_STEADY(); }
    else if (t + 1 < NT) { VMC("0"); }
    if (t + 1 < NT) barrier_();
    rb = (rb == 2) ? 0 : rb + 1;
    sb = (sb == 2) ? 0 : sb + 1;
  }

  // ---------------- epilogue ----------------
  int col16 = lane & 15, rgrp = lane >> 4;
#pragma unroll
  for (int mf = 0; mf < 4; ++mf) {
    int grow0 = bm * 256 + wm * 64 + mf * 16 + rgrp * 4;
#pragma unroll
    for (int nf = 0; nf < NI; ++nf) {
      int gc = bn * BN + wn * (NI * 16) + nf * 16 + col16;
      if constexpr (MODE == 0) {
        if (gc < 512) {  // z columns (nf-uniform: tile never straddles 512)
          float b = bza[gc];
#pragma unroll
          for (int j = 0; j < 4; ++j) {
            float z = sigmoidf_(acc[mf][nf][j] + b);
            Zb[(size_t)(grow0 + j) * 512 + gc] = (__bf16)z;
          }
        } else {       // r columns
          int c = gc - 512;
          float b = bzb[c];
#pragma unroll
          for (int j = 0; j < 4; ++j) {
            int grow = grow0 + j;
            float r = sigmoidf_(acc[mf][nf][j] + b);
            float hd = (float)A1[(size_t)grow * 1024 + 512 + c];
            RHout[(size_t)grow * 512 + c] = (__bf16)(r * hd);
          }
        }
      } else {
        float b = bza[gc];
#pragma unroll
        for (int j = 0; j < 4; ++j) {
          int grow = grow0 + j;
          float hh = tanhf(acc[mf][nf][j] + b);
          float hd = (float)A1[(size_t)grow * 1024 + 512 + gc];
          float z = (float)Zb[(size_t)grow * 512 + gc];
          out[(size_t)grow * 512 + gc] = (1.f - z) * hd + z * hh;
        }
      }
    }
  }
}

// ---------------- launch ----------------
extern "C" void kernel_launch(void* const* d_in, const int* in_sizes, int n_in,
                              void* d_out, int out_size, void* d_ws, size_t ws_size,
                              hipStream_t stream) {
  const float* inputs = (const float*)d_in[0];
  const float* h_prev = (const float*)d_in[1];
  const float* W_z = (const float*)d_in[2];
  const float* U_z = (const float*)d_in[3];
  const float* b_z = (const float*)d_in[4];
  const float* W_r = (const float*)d_in[5];
  const float* U_r = (const float*)d_in[6];
  const float* b_r = (const float*)d_in[7];
  const float* W_h = (const float*)d_in[8];
  const float* U_h = (const float*)d_in[9];
  const float* b_h = (const float*)d_in[10];
  const float* gxd = (const float*)d_in[11];
  const float* ghd = (const float*)d_in[12];
  const float* mimp = (const float*)d_in[13];
  float* out = (float*)d_out;

  char* ws = (char*)d_ws;
  __bf16* A1  = (__bf16*)(ws);                  // 16384x1024 bf16 = 32MB
  __bf16* RH  = (__bf16*)(ws + 33554432);       // 16384x512 bf16 = 16MB
  __bf16* Zb  = (__bf16*)(ws + 50331648);       // 16384x512 bf16 = 16MB
  __bf16* Wzr = (__bf16*)(ws + 67108864);       // 1024x1024 bf16 = 2MB
  __bf16* Wht = (__bf16*)(ws + 69206016);       // 512x1024 bf16  = 1MB

  prep_pack_k<<<2432, 256, 0, stream>>>(inputs, h_prev, gxd, ghd, mimp, A1,
                                        W_z, U_z, W_r, U_r, W_h, U_h, Wzr, Wht);
  gemm5_k<0><<<256, 512, 0, stream>>>(A1, RH, Wzr, Zb, RH, b_z, b_r, nullptr);
  gemm5_k<1><<<256, 512, 0, stream>>>(A1, RH, Wht, Zb, nullptr, b_h, nullptr, out);
}

// Round 12
// 119.561 us; speedup vs baseline: 1.0317x; 1.0317x over previous
//
#include <hip/hip_runtime.h>
#include <cmath>

// GRU-D cell: B=16384, F=U=512.
//   prep_pack: xd,hd -> A1=[xd|hd] bf16 (B x 1024); weights -> bf16 B^T
//   gemm5<0>: A1 @ Wzr -> sigmoid -> Zb (bf16), RH = r*hd (bf16)  [256x256]
//   gemm5<1>: [xd|RH] @ Wht -> tanh, blend with Zb, hd from A1 -> out [256x128]
// R12: prep via global_load_lds streaming. R9-R11 evidence: compiler refuses
// to keep >1-2 VGPR loads in flight (VGPR stuck at 32, 1.76 TB/s, three
// source-level ILP attempts null). global_load_lds needs no dest VGPRs ->
// allocator can't serialize it; 4-row chunks (32KB LDS) per block, one
// vmcnt(0)+barrier, compute from LDS, coalesced bf16x8 stores.
// pack + gemm5 kernels unchanged (passed 4x).

typedef __bf16 bf16x8 __attribute__((ext_vector_type(8)));
typedef __bf16 bf16x4 __attribute__((ext_vector_type(4)));
typedef float f32x4 __attribute__((ext_vector_type(4)));

typedef __attribute__((address_space(3))) void lds_vp;
typedef const __attribute__((address_space(1))) void g_vp;

#define VMC(N) asm volatile("s_waitcnt vmcnt(" N ")" ::: "memory")

__device__ __forceinline__ void barrier_() {
  asm volatile("" ::: "memory");
  __builtin_amdgcn_s_barrier();
  asm volatile("" ::: "memory");
}

__device__ __forceinline__ float sigmoidf_(float x) { return 1.f / (1.f + expf(-x)); }

// ---------------- prep (global_load_lds staged) + pack (LDS transpose) ----------------
__global__ __launch_bounds__(256) void prep_pack_k(
    const float* __restrict__ inp, const float* __restrict__ h_prev,
    const float* __restrict__ gxd, const float* __restrict__ ghd,
    const float* __restrict__ mimp, __bf16* __restrict__ A1,
    const float* __restrict__ Wz, const float* __restrict__ Uz,
    const float* __restrict__ Wr, const float* __restrict__ Ur,
    const float* __restrict__ Wh, const float* __restrict__ Uh,
    __bf16* __restrict__ Wzr, __bf16* __restrict__ Wht) {
  __shared__ __align__(16) float SHF[8192];   // 32KB, aliased by pack branch
  int tid = threadIdx.x;
  int lane = tid & 63, wid = tid >> 6;
  if (blockIdx.x < 4096) {
    int r0 = blockIdx.x * 4;                  // 4 rows per block
    // stage inp rows r0..r0+3 (24KB) + h_prev rows (8KB) into LDS, linear
    const char* gi = (const char*)(inp + (size_t)r0 * 1536);
    const char* gh = (const char*)(h_prev + (size_t)r0 * 512);
#pragma unroll
    for (int i = 0; i < 6; ++i) {
      int seg = i * 4 + wid;                  // 1KB segment
      __builtin_amdgcn_global_load_lds((g_vp*)(gi + seg * 1024 + lane * 16),
                                       (lds_vp*)((char*)SHF + seg * 1024), 16, 0, 0);
    }
#pragma unroll
    for (int i = 0; i < 2; ++i) {
      int seg = i * 4 + wid;
      __builtin_amdgcn_global_load_lds((g_vp*)(gh + seg * 1024 + lane * 16),
                                       (lds_vp*)((char*)SHF + 24576 + seg * 1024), 16, 0, 0);
    }
    // per-column params (L2-hot), hoisted before the drain
    int c8 = (tid & 63) << 3;
    int row2 = tid >> 7;                      // 0/1
    int half = (tid >> 6) & 1;                // 0: xd, 1: hd (wave-uniform)
    float gc[8], mi[8];
    if (half == 0) {
      float4 a = *(const float4*)(gxd + c8), b = *(const float4*)(gxd + c8 + 4);
      float4 p = *(const float4*)(mimp + c8), q = *(const float4*)(mimp + c8 + 4);
#pragma unroll
      for (int j = 0; j < 4; ++j) {
        gc[j] = -fmaxf(0.f, ((const float*)&a)[j]);
        gc[j + 4] = -fmaxf(0.f, ((const float*)&b)[j]);
        mi[j] = ((const float*)&p)[j];
        mi[j + 4] = ((const float*)&q)[j];
      }
    } else {
      float4 a = *(const float4*)(ghd + c8), b = *(const float4*)(ghd + c8 + 4);
#pragma unroll
      for (int j = 0; j < 4; ++j) {
        gc[j] = -fmaxf(0.f, ((const float*)&a)[j]);
        gc[j + 4] = -fmaxf(0.f, ((const float*)&b)[j]);
      }
    }
    VMC("0");
    barrier_();
#pragma unroll
    for (int u = 0; u < 2; ++u) {
      int row = u * 2 + row2;                 // 0..3
      bf16x8 o;
      if (half == 0) {
        const float* xr = &SHF[row * 1536 + c8];
        float xv[8], mv[8], dv[8];
        *(float4*)&xv[0] = *(const float4*)(xr);
        *(float4*)&xv[4] = *(const float4*)(xr + 4);
        *(float4*)&mv[0] = *(const float4*)(xr + 512);
        *(float4*)&mv[4] = *(const float4*)(xr + 516);
        *(float4*)&dv[0] = *(const float4*)(xr + 1024);
        *(float4*)&dv[4] = *(const float4*)(xr + 1028);
#pragma unroll
        for (int j = 0; j < 8; ++j) {
          float g = __expf(gc[j] * dv[j]);
          float xd = mv[j] * xv[j] + (1.f - mv[j]) * (g * xv[j] + (1.f - g) * mi[j]);
          o[j] = (__bf16)xd;
        }
        *(bf16x8*)(A1 + (size_t)(r0 + row) * 1024 + c8) = o;
      } else {
        const float* dr = &SHF[row * 1536 + 1024 + c8];
        const float* hr = &SHF[6144 + row * 512 + c8];
        float dv[8], hv[8];
        *(float4*)&dv[0] = *(const float4*)(dr);
        *(float4*)&dv[4] = *(const float4*)(dr + 4);
        *(float4*)&hv[0] = *(const float4*)(hr);
        *(float4*)&hv[4] = *(const float4*)(hr + 4);
#pragma unroll
        for (int j = 0; j < 8; ++j) {
          float hd = __expf(gc[j] * dv[j]) * hv[j];
          o[j] = (__bf16)hd;
        }
        *(bf16x8*)(A1 + (size_t)(r0 + row) * 1024 + 512 + c8) = o;
      }
    }
  } else {
    // pack one 64x64 (k,n) tile, transposed, into dst[n][k] (ldk=1024)
    __bf16* Tb = (__bf16*)SHF;                // [64][65] bf16 (8.3KB of SHF)
    int bid = blockIdx.x - 4096;
    const float* S;
    __bf16* dst;
    int tk, tn, nadj;
    if (bid < 256) {           // Wzr: 16 k-tiles x 16 n-tiles
      tk = (bid >> 4) * 64; tn = (bid & 15) * 64;
      bool khi = tk >= 512, nhi = tn >= 512;
      S = nhi ? (khi ? Ur : Wr) : (khi ? Uz : Wz);
      nadj = nhi ? 512 : 0;
      dst = Wzr;
    } else {                   // Wht: 16 k-tiles x 8 n-tiles
      int b2 = bid - 256;
      tk = (b2 >> 3) * 64; tn = (b2 & 7) * 64;
      S = (tk >= 512) ? Uh : Wh;
      nadj = 0;
      dst = Wht;
    }
    int kadj = (tk >= 512) ? 512 : 0;
    int kl = tid >> 4, n4 = (tid & 15) << 2;
#pragma unroll
    for (int rr = 0; rr < 4; ++rr) {
      int k = rr * 16 + kl;
      float4 v = *(const float4*)(S + (size_t)(tk - kadj + k) * 512 + (tn - nadj) + n4);
      Tb[k * 65 + n4 + 0] = (__bf16)v.x;
      Tb[k * 65 + n4 + 1] = (__bf16)v.y;
      Tb[k * 65 + n4 + 2] = (__bf16)v.z;
      Tb[k * 65 + n4 + 3] = (__bf16)v.w;
    }
    __syncthreads();
    int k0 = (tid & 7) * 8;
#pragma unroll
    for (int h = 0; h < 2; ++h) {
      int nl = (tid >> 3) + h * 32;
      bf16x8 v;
#pragma unroll
      for (int i = 0; i < 8; ++i) v[i] = Tb[(k0 + i) * 65 + nl];
      *(bf16x8*)(dst + (size_t)(tn + nl) * 1024 + tk + k0) = v;
    }
  }
}

// ---------------- 3-buffer GEMM (BM=256, BK=32, one block-round) ----------------
// LDS packed layout (16B units): logical element (row m, 16B k-chunk ku in 0..3)
// stored at unit (m>>1)*8 + (((m&1)*4 + ku) ^ ((m>>1)&7)).
// Staging writes linear units; per-lane global source applies the inverse map.

template <int MODE>
__global__ __launch_bounds__(512, 1) void gemm5_k(
    const __bf16* __restrict__ A1, const __bf16* __restrict__ RH,
    const __bf16* __restrict__ Bt,
    __bf16* __restrict__ Zb, __bf16* __restrict__ RHout,
    const float* __restrict__ bza, const float* __restrict__ bzb,
    float* __restrict__ out) {
  constexpr int NI = (MODE == 0) ? 8 : 4;     // n-frags per wave
  constexpr int BN = NI * 32;                 // 256 / 128
  constexpr int BUNITS = BN * 4;              // B 16B-units per tile
  constexpr int SBUF = 1024 + BUNITS;         // A 1024 | B
  __shared__ bf16x8 ldsv[3 * SBUF];           // 96KB / 72KB
  constexpr int NT = 32;                      // K=1024, BK=32
#define VMC_STEADY() do { if constexpr (MODE == 0) { VMC("4"); } else { VMC("3"); } } while (0)

  int bid = blockIdx.x;
  int swz = (bid & 7) * 32 + (bid >> 3);      // bijective XCD swizzle (256=8x32)
  int bm = swz >> 2, bn = swz & 3;            // 64 x 4
  int tid = threadIdx.x, lane = tid & 63, wid = tid >> 6;
  int wm = wid >> 1, wn = wid & 1;            // 4M x 2N waves: 64 x (NI*16)

  // per-lane staging source offsets (inverse of packed-swizzle map)
  auto inv = [&](int U, int ldb) {
    int r = U >> 3, s = (U & 7) ^ (r & 7);
    return (2 * r + (s >> 2)) * ldb + (s & 3) * 16;  // bytes
  };
  int UA0 = wid * 128 + lane, UA1 = UA0 + 64;
  int offA0 = inv(UA0, 2048), offA1 = inv(UA1, 2048);
  int offA0r = inv(UA0, 1024), offA1r = inv(UA1, 1024);  // MODE1 RH half
  int UB0 = (MODE == 0) ? (wid * 128 + lane) : (wid * 64 + lane);
  int offB0 = inv(UB0, 2048);
  int offB1 = (MODE == 0) ? inv(UB0 + 64, 2048) : 0;
  int ldsB = (MODE == 0) ? (wid * 128) : (wid * 64);   // wave-uniform

  auto stage = [&](int t, int buf) {
    const char* gA;
    int oA0, oA1;
    if (MODE == 0 || t < 16) {
      gA = (const char*)A1 + (size_t)bm * 256 * 2048 + t * 64;
      oA0 = offA0; oA1 = offA1;
    } else {
      gA = (const char*)RH + (size_t)bm * 256 * 1024 + (t - 16) * 64;
      oA0 = offA0r; oA1 = offA1r;
    }
    __builtin_amdgcn_global_load_lds((g_vp*)(gA + oA0),
        (lds_vp*)(ldsv + buf * SBUF + wid * 128), 16, 0, 0);
    __builtin_amdgcn_global_load_lds((g_vp*)(gA + oA1),
        (lds_vp*)(ldsv + buf * SBUF + wid * 128 + 64), 16, 0, 0);
    const char* gB = (const char*)Bt + (size_t)bn * BN * 2048 + t * 64;
    __builtin_amdgcn_global_load_lds((g_vp*)(gB + offB0),
        (lds_vp*)(ldsv + buf * SBUF + 1024 + ldsB), 16, 0, 0);
    if constexpr (MODE == 0) {
      __builtin_amdgcn_global_load_lds((g_vp*)(gB + offB1),
          (lds_vp*)(ldsv + buf * SBUF + 1024 + ldsB + 64), 16, 0, 0);
    }
  };

  // fragment read bases (16B units), loop-invariant
  int lr = (lane & 15) >> 1;
  int lo = ((lane & 1) << 2) | (lane >> 4);
  int aoff = lr * 8 + (lo ^ lr);
  int aB = wm * 256 + aoff;                   // + mf*64
  int bB = 1024 + wn * (NI * 64) + aoff;      // + nf*64

  f32x4 acc[4][NI] = {};

  stage(0, 0);
  stage(1, 1);
  VMC_STEADY();
  barrier_();

  int rb = 0, sb = 2;
  for (int t = 0; t < NT; ++t) {
    int base = rb * SBUF;
    if (t + 2 < NT) stage(t + 2, sb);

    bf16x8 bf[NI];
#pragma unroll
    for (int nf = 0; nf < NI; ++nf) bf[nf] = ldsv[base + bB + nf * 64];
    __builtin_amdgcn_s_setprio(1);
#pragma unroll
    for (int mf = 0; mf < 4; ++mf) {
      bf16x8 a = ldsv[base + aB + mf * 64];
#pragma unroll
      for (int nf = 0; nf < NI; ++nf)
        acc[mf][nf] = __builtin_amdgcn_mfma_f32_16x16x32_bf16(a, bf[nf],
                                                              acc[mf][nf], 0, 0, 0);
    }
    __builtin_amdgcn_s_setprio(0);

    if (t + 2 < NT) { VMC_STEADY(); }
    else if (t + 1 < NT) { VMC("0"); }
    if (t + 1 < NT) barrier_();
    rb = (rb == 2) ? 0 : rb + 1;
    sb = (sb == 2) ? 0 : sb + 1;
  }

  // ---------------- epilogue ----------------
  int col16 = lane & 15, rgrp = lane >> 4;
#pragma unroll
  for (int mf = 0; mf < 4; ++mf) {
    int grow0 = bm * 256 + wm * 64 + mf * 16 + rgrp * 4;
#pragma unroll
    for (int nf = 0; nf < NI; ++nf) {
      int gc = bn * BN + wn * (NI * 16) + nf * 16 + col16;
      if constexpr (MODE == 0) {
        if (gc < 512) {  // z columns (nf-uniform: tile never straddles 512)
          float b = bza[gc];
#pragma unroll
          for (int j = 0; j < 4; ++j) {
            float z = sigmoidf_(acc[mf][nf][j] + b);
            Zb[(size_t)(grow0 + j) * 512 + gc] = (__bf16)z;
          }
        } else {       // r columns
          int c = gc - 512;
          float b = bzb[c];
#pragma unroll
          for (int j = 0; j < 4; ++j) {
            int grow = grow0 + j;
            float r = sigmoidf_(acc[mf][nf][j] + b);
            float hd = (float)A1[(size_t)grow * 1024 + 512 + c];
            RHout[(size_t)grow * 512 + c] = (__bf16)(r * hd);
          }
        }
      } else {
        float b = bza[gc];
#pragma unroll
        for (int j = 0; j < 4; ++j) {
          int grow = grow0 + j;
          float hh = tanhf(acc[mf][nf][j] + b);
          float hd = (float)A1[(size_t)grow * 1024 + 512 + gc];
          float z = (float)Zb[(size_t)grow * 512 + gc];
          out[(size_t)grow * 512 + gc] = (1.f - z) * hd + z * hh;
        }
      }
    }
  }
}

// ---------------- launch ----------------
extern "C" void kernel_launch(void* const* d_in, const int* in_sizes, int n_in,
                              void* d_out, int out_size, void* d_ws, size_t ws_size,
                              hipStream_t stream) {
  const float* inputs = (const float*)d_in[0];
  const float* h_prev = (const float*)d_in[1];
  const float* W_z = (const float*)d_in[2];
  const float* U_z = (const float*)d_in[3];
  const float* b_z = (const float*)d_in[4];
  const float* W_r = (const float*)d_in[5];
  const float* U_r = (const float*)d_in[6];
  const float* b_r = (const float*)d_in[7];
  const float* W_h = (const float*)d_in[8];
  const float* U_h = (const float*)d_in[9];
  const float* b_h = (const float*)d_in[10];
  const float* gxd = (const float*)d_in[11];
  const float* ghd = (const float*)d_in[12];
  const float* mimp = (const float*)d_in[13];
  float* out = (float*)d_out;

  char* ws = (char*)d_ws;
  __bf16* A1  = (__bf16*)(ws);                  // 16384x1024 bf16 = 32MB
  __bf16* RH  = (__bf16*)(ws + 33554432);       // 16384x512 bf16 = 16MB
  __bf16* Zb  = (__bf16*)(ws + 50331648);       // 16384x512 bf16 = 16MB
  __bf16* Wzr = (__bf16*)(ws + 67108864);       // 1024x1024 bf16 = 2MB
  __bf16* Wht = (__bf16*)(ws + 69206016);       // 512x1024 bf16  = 1MB

  prep_pack_k<<<4480, 256, 0, stream>>>(inputs, h_prev, gxd, ghd, mimp, A1,
                                        W_z, U_z, W_r, U_r, W_h, U_h, Wzr, Wht);
  gemm5_k<0><<<256, 512, 0, stream>>>(A1, RH, Wzr, Zb, RH, b_z, b_r, nullptr);
  gemm5_k<1><<<256, 512, 0, stream>>>(A1, RH, Wht, Zb, nullptr, b_h, nullptr, out);
}